// Round 16
// baseline (152.693 us; speedup 1.0000x reference)
//
#include <hip/hip_runtime.h>
#include <math.h>

#define B_N 524288
#define C_N 40
constexpr int BLOCK  = 320;   // 5 waves; W = 320*4 = 1280 floats = 32 rows of C=40
constexpr int VEC    = 4;
constexpr int UNROLL = 4;     // 8 nt loads batched (champion no-spill batch)
constexpr int GRID   = 1024;  // 4 blocks/CU, single round (champion geometry)
constexpr int NREP   = 32;    // accumulator replicas to spread atomic contention

typedef float f32x4 __attribute__((ext_vector_type(4)));

// Nontemporal streaming load (bypass L1 allocation) — R9's proven win.
__device__ __forceinline__ f32x4 ldnt(const float* p) {
    return __builtin_nontemporal_load(reinterpret_cast<const f32x4*>(p));
}

// R9 champion main loop (93% of m13's measured per-CU read rate) + fused
// finalization: the last-arriving block reduces the NREP replicas and
// writes the scalar loss (threadfence-reduction pattern), eliminating the
// second kernel launch + inter-kernel gap.
__global__ __launch_bounds__(BLOCK) void bdl_accum(
    const float* __restrict__ pred, const float* __restrict__ tgt,
    float* __restrict__ gacc, unsigned* __restrict__ counter,
    float* __restrict__ out)
{
    constexpr float  LN9    = 2.1972245773362196f;
    constexpr int    W      = BLOCK * VEC;                   // 1280 (== 0 mod 40)
    constexpr size_t TILE   = (size_t)W * UNROLL;            // 5120
    constexpr size_t STRIDE = (size_t)GRID * TILE;
    constexpr size_t TOTAL  = (size_t)B_N * C_N;

    float cntp[VEC] = {0.f,0.f,0.f,0.f};
    float sall[VEC] = {0.f,0.f,0.f,0.f};
    float spos[VEC] = {0.f,0.f,0.f,0.f};
    float spe[VEC]  = {0.f,0.f,0.f,0.f};
    float sne[VEC]  = {0.f,0.f,0.f,0.f};

    const int tid = threadIdx.x;

    for (size_t base = (size_t)blockIdx.x * TILE + (size_t)tid * VEC;
         base < TOTAL; base += STRIDE) {
        f32x4 p[UNROLL], t[UNROLL];
        #pragma unroll
        for (int u = 0; u < UNROLL; ++u) {
            p[u] = ldnt(pred + base + (size_t)u * W);
            t[u] = ldnt(tgt  + base + (size_t)u * W);
        }
        #pragma unroll
        for (int u = 0; u < UNROLL; ++u) {
            #pragma unroll
            for (int j = 0; j < VEC; ++j) {
                const float x  = p[u][j];
                const float tv = t[u][j];
                const float e  = __expf(-fabsf(x));
                const float sp_ = __logf(1.f + e);            // softplus(-|x|)
                const float bce = sp_ + fmaxf(x, 0.f) - x * tv;
                const float bpos = (x >  LN9) ? bce : 0.f;    // easy positive
                const float bneg = (x < -LN9) ? bce : 0.f;    // easy negative
                cntp[j] += tv;
                sall[j] += bce;
                spos[j]  = fmaf(tv, bce,   spos[j]);
                spe[j]   = fmaf(tv, bpos,  spe[j]);           // t * easy-pos
                sne[j]   = fmaf(-tv, bneg, sne[j] + bneg);    // (1-t) * easy-neg
            }
        }
    }

    __shared__ float lacc[C_N * 5];
    __shared__ int   is_last;
    if (tid < C_N * 5) lacc[tid] = 0.f;
    __syncthreads();
    const int c0 = (tid * VEC) % C_N;          // constant classes per thread
    #pragma unroll
    for (int j = 0; j < VEC; ++j) {
        float* a = &lacc[(c0 + j) * 5];
        atomicAdd(a + 0, cntp[j]);
        atomicAdd(a + 1, sall[j]);
        atomicAdd(a + 2, spos[j]);
        atomicAdd(a + 3, spe[j]);
        atomicAdd(a + 4, sne[j]);
    }
    __syncthreads();
    if (tid < C_N * 5)
        atomicAdd(&gacc[(blockIdx.x % NREP) * (C_N * 5) + tid], lacc[tid]);

    // ---- last-block finalization (threadfence reduction pattern) ----
    __threadfence();                            // our adds visible device-wide
    __syncthreads();
    if (tid == 0) {
        const unsigned old = __hip_atomic_fetch_add(
            counter, 1u, __ATOMIC_ACQ_REL, __HIP_MEMORY_SCOPE_AGENT);
        is_last = (old == GRID - 1);
    }
    __syncthreads();
    if (!is_last) return;

    if (tid < C_N * 5) {                        // re-reduce replicas (scoped loads)
        float s = 0.f;
        #pragma unroll
        for (int r = 0; r < NREP; ++r)
            s += __hip_atomic_load(&gacc[r * (C_N * 5) + tid],
                                   __ATOMIC_RELAXED, __HIP_MEMORY_SCOPE_AGENT);
        lacc[tid] = s;
    }
    __syncthreads();
    if (tid == 0) {
        const float Bf  = (float)B_N;
        const float bal = 0.5f * Bf;            // PROP * batch
        float tot = 0.f;
        for (int c = 0; c < C_N; ++c) {
            const float cp  = lacc[c * 5 + 0];
            const float sa  = lacc[c * 5 + 1];
            const float sp  = lacc[c * 5 + 2];
            const float se  = lacc[c * 5 + 3];
            const float sne_= lacc[c * 5 + 4];
            const float sn  = sa - sp;
            const bool posmaj = (cp >= bal);    // pos_gt; else neg_gt
            const float nmaj = posmaj ? cp : (Bf - cp);
            const float nmin = Bf - nmaj;
            const float smaj = posmaj ? (sp - se) : (sn - sne_);
            const float smin = posmaj ? sn : sp;
            const float wmaj = bal / fmaxf(nmaj, 1.f);
            const float wmin = (nmin > 0.f) ? ((Bf - bal) / fmaxf(nmin, 1.f)) : 1.f;
            tot += smaj * wmaj + smin * wmin;
        }
        out[0] = tot / (Bf * (float)C_N);
    }
}

extern "C" void kernel_launch(void* const* d_in, const int* in_sizes, int n_in,
                              void* d_out, int out_size, void* d_ws, size_t ws_size,
                              hipStream_t stream) {
    const float* pred = (const float*)d_in[0];
    const float* tgt  = (const float*)d_in[1];
    float*    gacc    = (float*)d_ws;                     // NREP*200 floats
    unsigned* counter = (unsigned*)((char*)d_ws + NREP * C_N * 5 * sizeof(float));
    hipMemsetAsync(d_ws, 0, NREP * C_N * 5 * sizeof(float) + sizeof(unsigned), stream);
    bdl_accum<<<GRID, BLOCK, 0, stream>>>(pred, tgt, gacc, counter, (float*)d_out);
}

// Round 17
// 64.028 us; speedup vs baseline: 2.3848x; 2.3848x over previous
//
#include <hip/hip_runtime.h>
#include <math.h>

#define B_N 524288
#define C_N 40
constexpr int BLOCK  = 320;   // 5 waves; W = 320*4 = 1280 floats = 32 rows of C=40
constexpr int VEC    = 4;
constexpr int UNROLL = 4;     // 8 nt loads batched (champion no-spill batch)
constexpr int GRID   = 1024;  // 4 blocks/CU, single round (champion geometry)
constexpr int NREP   = 32;    // accumulator replicas to spread atomic contention

typedef float f32x4 __attribute__((ext_vector_type(4)));

// Nontemporal streaming load (bypass L1 allocation) — the session's one
// decisive win (+27%): streaming floats at 20 waves/CU thrash the 32KB L1
// allocation path; nt skips it.
__device__ __forceinline__ f32x4 ldnt(const float* p) {
    return __builtin_nontemporal_load(reinterpret_cast<const f32x4*>(p));
}

// CHAMPION (R9): 2.93 TB/s demand-read = ~93% of the measured per-CU read
// ceiling (m13 copy read-side). VALU 25%, HBM 18%, occ 36% — the limiter is
// the CU<->L2 return path, which no tested ILP/TLP/DMA/churn config beat.
__global__ __launch_bounds__(BLOCK) void bdl_accum(
    const float* __restrict__ pred, const float* __restrict__ tgt,
    float* __restrict__ gacc)
{
    constexpr float  LN9    = 2.1972245773362196f;
    constexpr int    W      = BLOCK * VEC;                   // 1280 (== 0 mod 40)
    constexpr size_t TILE   = (size_t)W * UNROLL;            // 5120
    constexpr size_t STRIDE = (size_t)GRID * TILE;
    constexpr size_t TOTAL  = (size_t)B_N * C_N;

    float cntp[VEC] = {0.f,0.f,0.f,0.f};
    float sall[VEC] = {0.f,0.f,0.f,0.f};
    float spos[VEC] = {0.f,0.f,0.f,0.f};
    float spe[VEC]  = {0.f,0.f,0.f,0.f};
    float sne[VEC]  = {0.f,0.f,0.f,0.f};

    const int tid = threadIdx.x;

    for (size_t base = (size_t)blockIdx.x * TILE + (size_t)tid * VEC;
         base < TOTAL; base += STRIDE) {
        f32x4 p[UNROLL], t[UNROLL];
        #pragma unroll
        for (int u = 0; u < UNROLL; ++u) {
            p[u] = ldnt(pred + base + (size_t)u * W);
            t[u] = ldnt(tgt  + base + (size_t)u * W);
        }
        #pragma unroll
        for (int u = 0; u < UNROLL; ++u) {
            #pragma unroll
            for (int j = 0; j < VEC; ++j) {
                const float x  = p[u][j];
                const float tv = t[u][j];
                const float e  = __expf(-fabsf(x));
                const float sp_ = __logf(1.f + e);            // softplus(-|x|)
                const float bce = sp_ + fmaxf(x, 0.f) - x * tv;
                const float bpos = (x >  LN9) ? bce : 0.f;    // easy positive
                const float bneg = (x < -LN9) ? bce : 0.f;    // easy negative
                cntp[j] += tv;
                sall[j] += bce;
                spos[j]  = fmaf(tv, bce,   spos[j]);
                spe[j]   = fmaf(tv, bpos,  spe[j]);           // t * easy-pos
                sne[j]   = fmaf(-tv, bneg, sne[j] + bneg);    // (1-t) * easy-neg
            }
        }
    }

    __shared__ float lacc[C_N * 5];
    if (tid < C_N * 5) lacc[tid] = 0.f;
    __syncthreads();
    const int c0 = (tid * VEC) % C_N;          // constant classes per thread
    #pragma unroll
    for (int j = 0; j < VEC; ++j) {
        float* a = &lacc[(c0 + j) * 5];
        atomicAdd(a + 0, cntp[j]);
        atomicAdd(a + 1, sall[j]);
        atomicAdd(a + 2, spos[j]);
        atomicAdd(a + 3, spe[j]);
        atomicAdd(a + 4, sne[j]);
    }
    __syncthreads();
    if (tid < C_N * 5)
        atomicAdd(&gacc[(blockIdx.x % NREP) * (C_N * 5) + tid], lacc[tid]);
}

__global__ void bdl_final(const float* __restrict__ gacc, float* __restrict__ out)
{
    __shared__ float acc[C_N * 5];
    const int tid = threadIdx.x;
    if (tid < C_N * 5) {
        float s = 0.f;
        #pragma unroll
        for (int r = 0; r < NREP; ++r) s += gacc[r * (C_N * 5) + tid];
        acc[tid] = s;
    }
    __syncthreads();
    if (tid == 0) {
        const float Bf  = (float)B_N;
        const float bal = 0.5f * Bf;               // PROP * batch
        float tot = 0.f;
        for (int c = 0; c < C_N; ++c) {
            const float cntp = acc[c * 5 + 0];
            const float sall = acc[c * 5 + 1];
            const float sp   = acc[c * 5 + 2];
            const float spe  = acc[c * 5 + 3];
            const float sne  = acc[c * 5 + 4];
            const float sn   = sall - sp;
            const bool posmaj = (cntp >= bal);     // pos_gt; else neg_gt
            const float nmaj = posmaj ? cntp : (Bf - cntp);
            const float nmin = Bf - nmaj;
            const float smaj = posmaj ? (sp - spe) : (sn - sne);
            const float smin = posmaj ? sn : sp;
            const float wmaj = bal / fmaxf(nmaj, 1.f);
            const float wmin = (nmin > 0.f) ? ((Bf - bal) / fmaxf(nmin, 1.f)) : 1.f;
            tot += smaj * wmaj + smin * wmin;
        }
        out[0] = tot / (Bf * (float)C_N);
    }
}

extern "C" void kernel_launch(void* const* d_in, const int* in_sizes, int n_in,
                              void* d_out, int out_size, void* d_ws, size_t ws_size,
                              hipStream_t stream) {
    const float* pred = (const float*)d_in[0];
    const float* tgt  = (const float*)d_in[1];
    float* gacc = (float*)d_ws;                       // NREP*200 floats = 25.6 KB
    hipMemsetAsync(gacc, 0, NREP * C_N * 5 * sizeof(float), stream);
    bdl_accum<<<GRID, BLOCK, 0, stream>>>(pred, tgt, gacc);
    bdl_final<<<1, 256, 0, stream>>>(gacc, (float*)d_out);
}